// Round 1
// 10170.535 us; speedup vs baseline: 1.3441x; 1.3441x over previous
//
#include <hip/hip_runtime.h>
#include <hip/hip_bf16.h>

// ---------------- sizes ----------------
#define H    400
#define SEG  416          // per-layer feature segment, padded to 13*32
#define G4   1600         // 4*H gate rows
#define TT   1024
#define BB   64
#define NOUT 121
#define KS0  13           // k-steps for K=416
#define KS12 26           // k-steps for K=832
#define FPAD 1248         // 3*SEG
#define KSL  39           // 1248/32
#define NG   25           // producer WGs per layer

typedef __attribute__((ext_vector_type(8))) short bf16x8;
typedef __attribute__((ext_vector_type(4))) float f32x4;
typedef unsigned short u16;

// ---------------- persistent device state ----------------
// bf16 history of all three layers' h, padded segments; also the final-GEMM A.
__device__ u16   g_outs[BB * TT][FPAD];
__device__ u16   g_pk0[100][KS0][512];    // packed weights, MFMA-B order
__device__ u16   g_pk1[100][KS12][512];
__device__ u16   g_pk2[100][KS12][512];
__device__ u16   g_pkl[8][KSL][512];
__device__ float g_bsum[3][G4];           // bih+bhh
__device__ float g_wx[3][G4][3];          // Wih x-part (first 3 cols)
__device__ float g_bl[128];
__device__ int   g_done[3][TT][32];       // [l][t][0], 128B-strided counters
__device__ int   g_abort;

// ---------------- helpers ----------------
__device__ inline u16 f2b(float f) {
  union { float f; unsigned u; } v; v.f = f;
  unsigned r = v.u + 0x7FFF + ((v.u >> 16) & 1);
  return (u16)(r >> 16);
}
__device__ inline float sigm(float x) { return 1.f / (1.f + __expf(-x)); }
__device__ inline float tanh_(float x) { return 2.f * sigm(2.f * x) - 1.f; }

__device__ inline int wait_ge25(int* p) {
  long n = 0;
  while (__hip_atomic_load(p, __ATOMIC_ACQUIRE, __HIP_MEMORY_SCOPE_AGENT) < NG) {
    ++n;
    if ((n & 255) == 0) {
      if (__hip_atomic_load(&g_abort, __ATOMIC_RELAXED, __HIP_MEMORY_SCOPE_AGENT)) return 1;
      if (n > (1L << 22)) {   // ~0.5-1 s: protocol failed; abort everyone
        __hip_atomic_store(&g_abort, 1, __ATOMIC_RELAXED, __HIP_MEMORY_SCOPE_AGENT);
        return 1;
      }
    }
    __builtin_amdgcn_s_sleep(1);
  }
  return 0;
}

// ---------------- setup kernels ----------------
__global__ void k_zero() {
  int i = blockIdx.x * blockDim.x + threadIdx.x;
  if (i == 0) g_abort = 0;
  if (i < 3 * TT * 32) (&g_done[0][0][0])[i] = 0;
  if (i < BB * TT * 24) {                  // zero pad columns (cols 400..415 of each segment)
    int r = i / 24, j = i % 24;
    int seg = j >> 3, w = j & 7;
    *(unsigned*)&g_outs[r][seg * SEG + 400 + w * 2] = 0u;
  }
}

__global__ void k_pack_rec(const float* Wih, const float* Whh, int layer,
                           int ksteps, int kin) {
  int i = blockIdx.x * blockDim.x + threadIdx.x;
  int total = 100 * ksteps * 512;
  if (i >= total) return;
  int j = i & 7, lane = (i >> 3) & 63;
  int ks = (i >> 9) % ksteps, nt = (i >> 9) / ksteps;
  int g = nt / 25, jt = nt % 25;
  int n  = g * 400 + jt * 16 + (lane & 15);     // gate row
  int kk = (lane >> 4) * 8 + j;                 // k within 32-chunk
  float v = 0.f;
  if (layer == 0) {
    int k = ks * 32 + kk;
    if (k < H) v = Whh[n * H + k];
  } else {
    if (ks < KS0) { int k = ks * 32 + kk;         if (k < H) v = Wih[n * kin + 3 + k]; }
    else          { int k = (ks - KS0) * 32 + kk; if (k < H) v = Whh[n * H + k]; }
  }
  u16* dst = (layer == 0) ? &g_pk0[0][0][0] : (layer == 1 ? &g_pk1[0][0][0] : &g_pk2[0][0][0]);
  dst[i] = f2b(v);
}

__global__ void k_pack_wl(const float* Wl, const float* bl) {
  int i = blockIdx.x * blockDim.x + threadIdx.x;
  if (i < 128) g_bl[i] = (i < NOUT) ? bl[i] : 0.f;
  int total = 8 * KSL * 512;
  if (i >= total) return;
  int j = i & 7, lane = (i >> 3) & 63;
  int ks = (i >> 9) % KSL, nt = (i >> 9) / KSL;
  int n = nt * 16 + (lane & 15);
  int k = ks * 32 + (lane >> 4) * 8 + j;        // 0..1247 in padded feature space
  int seg = k / SEG, jj = k - seg * SEG;
  float v = 0.f;
  if (n < NOUT && jj < 400) v = Wl[n * 1200 + seg * 400 + jj];
  (&g_pkl[0][0][0])[i] = f2b(v);
}

__global__ void k_pack_misc(const float* Wih0, const float* bih0, const float* bhh0,
                            const float* Wih1, const float* bih1, const float* bhh1,
                            const float* Wih2, const float* bih2, const float* bhh2) {
  int i = blockIdx.x * blockDim.x + threadIdx.x;
  if (i >= 3 * G4) return;
  int l = i / G4, n = i % G4;
  const float* bi = l == 0 ? bih0 : (l == 1 ? bih1 : bih2);
  const float* bh = l == 0 ? bhh0 : (l == 1 ? bhh1 : bhh2);
  const float* wi = l == 0 ? Wih0 : (l == 1 ? Wih1 : Wih2);
  int kin = l == 0 ? 3 : 403;
  g_bsum[l][n] = bi[n] + bh[n];
  for (int c = 0; c < 3; ++c) g_wx[l][n][c] = wi[n * kin + c];
}

// ---------------- persistent pipelined LSTM ----------------
// 75 WGs = 3 layers x 25 col-tiles; 256 threads = 4 waves.
// L0:   wave wv owns mtile wv (16 batches), full K=13, all 4 gates.
// L1/2: wave (kh=wv&1, mh=wv>>1) computes mtiles {2mh,2mh+1} for k-half kh;
//       split-K partials exchanged through LDS; wave epilogues mtile 2mh+kh.
// Weights register-resident (52 bf16x8 = 208 VGPR); c-state register-resident.
__global__ __launch_bounds__(256, 1) void k_lstm(const float* __restrict__ X) {
  const int wg = blockIdx.x;
  const int l = wg / 25, jt = wg % 25;
  const int tid = threadIdx.x;
  const int lane = tid & 63;
  const int wv = tid >> 6;
  const int brow = lane & 15;
  const int kg = lane >> 4;
  const int jh = jt * 16 + brow;

  const int kh = (l == 0) ? 0 : (wv & 1);
  const int mh = (l == 0) ? wv : (wv >> 1);
  const int m_own = (l == 0) ? mh : (mh * 2 + kh);

  const u16* pk = (l == 0) ? &g_pk0[0][0][0] : (l == 1 ? &g_pk1[0][0][0] : &g_pk2[0][0][0]);
  const int nks = (l == 0) ? KS0 : KS12;
  const int kofs = (l == 0) ? 0 : kh * 13;

  bf16x8 Bf[4][13];
#pragma unroll
  for (int g = 0; g < 4; ++g)
#pragma unroll
    for (int ks = 0; ks < 13; ++ks)
      Bf[g][ks] = *(const bf16x8*)&pk[(((g * 25 + jt) * nks + kofs + ks) * 64 + lane) * 8];

  float bsum[4], wxc[4][3];
#pragma unroll
  for (int g = 0; g < 4; ++g) {
    int n = g * 400 + jh;
    bsum[g] = g_bsum[l][n];
    wxc[g][0] = g_wx[l][n][0];
    wxc[g][1] = g_wx[l][n][1];
    wxc[g][2] = g_wx[l][n][2];
  }

  float cst[4] = {0.f, 0.f, 0.f, 0.f};
  const long xbase = (long)(m_own * 16 + kg * 4) * TT * 3;

  __shared__ float red[4][64][20];   // 80B lane stride: 16B-aligned, conflict-free b128
  __shared__ int s_abort;

  for (int t = 0; t < TT; ++t) {
    // ---------- wait for producers ----------
    if (tid == 0) {
      int ab = 0;
      if (l > 0) ab |= wait_ge25(&g_done[l - 1][t][0]);
      if (t > 0) ab |= wait_ge25(&g_done[l][t - 1][0]);
      s_abort = ab;
    }
    __syncthreads();
    if (s_abort) return;

    // ---------- MFMA ----------
    f32x4 acc0[4] = {}, acc1[4] = {};
    if (l == 0) {
      if (t > 0) {
        const int row = (m_own * 16 + brow) * TT + (t - 1);
        const int co = kg * 8;
#pragma unroll
        for (int ks = 0; ks < 13; ++ks) {
          bf16x8 a = *(const bf16x8*)&g_outs[row][co + ks * 32];
#pragma unroll
          for (int g = 0; g < 4; ++g)
            acc0[g] = __builtin_amdgcn_mfma_f32_16x16x32_bf16(a, Bf[g][ks], acc0[g], 0, 0, 0);
        }
      }
    } else {
      if (kh == 0 || t > 0) {          // kh=1 at t=0: h_self(-1)=0, skip
        const int ts = kh ? (t - 1) : t;
        const int seg = kh ? l : (l - 1);
        const int r0 = (mh * 32 + brow) * TT + ts;
        const int r1 = r0 + 16 * TT;
        const int co = seg * SEG + kg * 8;
#pragma unroll
        for (int ks = 0; ks < 13; ++ks) {
          bf16x8 a0 = *(const bf16x8*)&g_outs[r0][co + ks * 32];
          bf16x8 a1 = *(const bf16x8*)&g_outs[r1][co + ks * 32];
#pragma unroll
          for (int g = 0; g < 4; ++g) {
            acc0[g] = __builtin_amdgcn_mfma_f32_16x16x32_bf16(a0, Bf[g][ks], acc0[g], 0, 0, 0);
            acc1[g] = __builtin_amdgcn_mfma_f32_16x16x32_bf16(a1, Bf[g][ks], acc1[g], 0, 0, 0);
          }
        }
      }
    }

    // ---------- split-K reduce (l>0) ----------
    f32x4 gacc[4];
    if (l == 0) {
#pragma unroll
      for (int g = 0; g < 4; ++g) gacc[g] = acc0[g];
    } else {
#pragma unroll
      for (int g = 0; g < 4; ++g)
        *(f32x4*)&red[wv][lane][g * 4] = kh ? acc0[g] : acc1[g];  // partial for mtile NOT owned
      __syncthreads();
#pragma unroll
      for (int g = 0; g < 4; ++g)
        gacc[g] = (kh ? acc1[g] : acc0[g]) + *(const f32x4*)&red[wv ^ 1][lane][g * 4];
    }

    // ---------- epilogue: gates -> c,h ----------
    const float* xp = X + xbase + (long)t * 3;
#pragma unroll
    for (int r = 0; r < 4; ++r) {
      float x0 = xp[(long)r * TT * 3 + 0];
      float x1 = xp[(long)r * TT * 3 + 1];
      float x2 = xp[(long)r * TT * 3 + 2];
      float gate[4];
#pragma unroll
      for (int g = 0; g < 4; ++g)
        gate[g] = gacc[g][r] + bsum[g] + wxc[g][0] * x0 + wxc[g][1] * x1 + wxc[g][2] * x2;
      float ig = sigm(gate[0]), fg = sigm(gate[1]);
      float gg = tanh_(gate[2]), og = sigm(gate[3]);
      float c = fg * cst[r] + ig * gg;
      cst[r] = c;
      float h = og * tanh_(c);
      g_outs[(long)(m_own * 16 + kg * 4 + r) * TT + t][l * SEG + jh] = f2b(h);
    }

    // ---------- publish ----------
    __syncthreads();   // drains vmcnt for all waves' h stores
    if (tid == 0)
      __hip_atomic_fetch_add(&g_done[l][t][0], 1, __ATOMIC_RELEASE, __HIP_MEMORY_SCOPE_AGENT);
  }
}

// ---------------- final projection: [65536,1248] x [1248,128] ----------------
__global__ __launch_bounds__(256) void k_final(float* __restrict__ out) {
  int mt   = blockIdx.x * 4 + (threadIdx.x >> 6);
  int lane = threadIdx.x & 63;
  int arow = mt * 16 + (lane & 15);
  int kchunk = (lane >> 4) * 8;
  f32x4 acc[8] = {};
  for (int ks = 0; ks < KSL; ++ks) {
    bf16x8 a = *(const bf16x8*)&g_outs[arow][ks * 32 + kchunk];
#pragma unroll
    for (int nt = 0; nt < 8; ++nt) {
      bf16x8 b = *(const bf16x8*)&g_pkl[nt][ks][lane * 8];
      acc[nt] = __builtin_amdgcn_mfma_f32_16x16x32_bf16(a, b, acc[nt], 0, 0, 0);
    }
  }
#pragma unroll
  for (int nt = 0; nt < 8; ++nt) {
    int o = nt * 16 + (lane & 15);
    if (o >= NOUT) continue;
#pragma unroll
    for (int r = 0; r < 4; ++r) {
      int m = mt * 16 + (lane >> 4) * 4 + r;
      out[(long)m * NOUT + o] = acc[nt][r] + g_bl[o];
    }
  }
}

// ---------------- launch ----------------
extern "C" void kernel_launch(void* const* d_in, const int* in_sizes, int n_in,
                              void* d_out, int out_size, void* d_ws, size_t ws_size,
                              hipStream_t stream) {
  const float* X    = (const float*)d_in[0];
  const float* Wih0 = (const float*)d_in[1];
  const float* Whh0 = (const float*)d_in[2];
  const float* bih0 = (const float*)d_in[3];
  const float* bhh0 = (const float*)d_in[4];
  const float* Wih1 = (const float*)d_in[5];
  const float* Whh1 = (const float*)d_in[6];
  const float* bih1 = (const float*)d_in[7];
  const float* bhh1 = (const float*)d_in[8];
  const float* Wih2 = (const float*)d_in[9];
  const float* Whh2 = (const float*)d_in[10];
  const float* bih2 = (const float*)d_in[11];
  const float* bhh2 = (const float*)d_in[12];
  const float* Wl   = (const float*)d_in[13];
  const float* bl   = (const float*)d_in[14];

  k_zero<<<(BB * TT * 24 + 255) / 256, 256, 0, stream>>>();
  k_pack_rec<<<(100 * KS0  * 512 + 255) / 256, 256, 0, stream>>>(nullptr, Whh0, 0, KS0, 3);
  k_pack_rec<<<(100 * KS12 * 512 + 255) / 256, 256, 0, stream>>>(Wih1, Whh1, 1, KS12, 403);
  k_pack_rec<<<(100 * KS12 * 512 + 255) / 256, 256, 0, stream>>>(Wih2, Whh2, 2, KS12, 403);
  k_pack_wl<<<(8 * KSL * 512 + 255) / 256, 256, 0, stream>>>(Wl, bl);
  k_pack_misc<<<(3 * G4 + 255) / 256, 256, 0, stream>>>(Wih0, bih0, bhh0,
                                                        Wih1, bih1, bhh1,
                                                        Wih2, bih2, bhh2);
  k_lstm<<<75, 256, 0, stream>>>(X);
  k_final<<<1024, 256, 0, stream>>>((float*)d_out);
}

// Round 2
// 5287.625 us; speedup vs baseline: 2.5853x; 1.9235x over previous
//
#include <hip/hip_runtime.h>
#include <hip/hip_bf16.h>

// ---------------- sizes ----------------
#define H    400
#define SEG  416          // per-layer feature segment, padded to 13*32
#define G4   1600         // 4*H gate rows
#define TT   1024
#define BB   64
#define NOUT 121
#define KS0  13           // k-steps for K=416
#define KS12 26           // k-steps for K=832
#define FPAD 1248         // 3*SEG
#define KSL  39           // 1248/32
#define NG   25           // producer WGs per (layer, batch-group) flag

typedef __attribute__((ext_vector_type(8))) short bf16x8;
typedef __attribute__((ext_vector_type(4))) float f32x4;
typedef unsigned short u16;

// ---------------- persistent device state ----------------
__device__ __align__(16) u16   g_outs[BB * TT][FPAD];
__device__ __align__(16) u16   g_pk0[100][KS0][512];
__device__ __align__(16) u16   g_pk1[100][KS12][512];
__device__ __align__(16) u16   g_pk2[100][KS12][512];
__device__ __align__(16) u16   g_pkl[8][KSL][512];
__device__ float g_bsum[3][G4];
__device__ float g_wx[3][G4][3];
__device__ float g_bl[128];
__device__ int   g_flag[3][2][TT][32];    // [l][bg][t][0], 128B-strided
__device__ int   g_abort;

// ---------------- helpers ----------------
__device__ inline u16 f2b(float f) {
  union { float f; unsigned u; } v; v.f = f;
  unsigned r = v.u + 0x7FFF + ((v.u >> 16) & 1);
  return (u16)(r >> 16);
}
__device__ inline float sigm(float x) { return 1.f / (1.f + __expf(-x)); }
__device__ inline float tanh_(float x) { return 2.f * sigm(2.f * x) - 1.f; }

// coherent-point (cross-XCD safe) accessors: sc0 sc1 = bypass L1+L2, no inv/wb fences
__device__ inline void gstore_sc(u16* p, unsigned v) {
  asm volatile("global_store_short %0, %1, off sc0 sc1" :: "v"(p), "v"(v) : "memory");
}
__device__ inline void flag_add(int* p) {
  int one = 1;
  asm volatile("global_atomic_add %0, %1, off sc1" :: "v"(p), "v"(one) : "memory");
}
__device__ inline int poll_once(const int* p) {
  int v;
  asm volatile("global_load_dword %0, %1, off sc0 sc1\n\ts_waitcnt vmcnt(0)"
               : "=v"(v) : "v"(p) : "memory");
  return v;
}
// returns 1 on abort
__device__ inline int wait_flag(const int* p) {
  long n = 0;
  while (poll_once(p) < NG) {
    if ((++n & 1023) == 0) {
      if (poll_once(&g_abort)) return 1;
      if (n > (1L << 21)) {
        __hip_atomic_store(&g_abort, 1, __ATOMIC_RELAXED, __HIP_MEMORY_SCOPE_AGENT);
        return 1;
      }
    }
  }
  return 0;
}

// ---------------- setup kernels ----------------
__global__ void k_zero() {
  int i = blockIdx.x * blockDim.x + threadIdx.x;
  if (i == 0) g_abort = 0;
  if (i < 3 * 2 * TT * 32) (&g_flag[0][0][0][0])[i] = 0;
  if (i < BB * TT * 24) {                  // zero pad columns (cols 400..415 of each segment)
    int r = i / 24, j = i % 24;
    int seg = j >> 3, w = j & 7;
    *(unsigned*)&g_outs[r][seg * SEG + 400 + w * 2] = 0u;
  }
}

__global__ void k_pack_rec(const float* Wih, const float* Whh, int layer,
                           int ksteps, int kin) {
  int i = blockIdx.x * blockDim.x + threadIdx.x;
  int total = 100 * ksteps * 512;
  if (i >= total) return;
  int j = i & 7, lane = (i >> 3) & 63;
  int ks = (i >> 9) % ksteps, nt = (i >> 9) / ksteps;
  int g = nt / 25, jt = nt % 25;
  int n  = g * 400 + jt * 16 + (lane & 15);
  int kk = (lane >> 4) * 8 + j;
  float v = 0.f;
  if (layer == 0) {
    int k = ks * 32 + kk;
    if (k < H) v = Whh[n * H + k];
  } else {
    if (ks < KS0) { int k = ks * 32 + kk;         if (k < H) v = Wih[n * kin + 3 + k]; }
    else          { int k = (ks - KS0) * 32 + kk; if (k < H) v = Whh[n * H + k]; }
  }
  u16* dst = (layer == 0) ? &g_pk0[0][0][0] : (layer == 1 ? &g_pk1[0][0][0] : &g_pk2[0][0][0]);
  dst[i] = f2b(v);
}

__global__ void k_pack_wl(const float* Wl, const float* bl) {
  int i = blockIdx.x * blockDim.x + threadIdx.x;
  if (i < 128) g_bl[i] = (i < NOUT) ? bl[i] : 0.f;
  int total = 8 * KSL * 512;
  if (i >= total) return;
  int j = i & 7, lane = (i >> 3) & 63;
  int ks = (i >> 9) % KSL, nt = (i >> 9) / KSL;
  int n = nt * 16 + (lane & 15);
  int k = ks * 32 + (lane >> 4) * 8 + j;
  int seg = k / SEG, jj = k - seg * SEG;
  float v = 0.f;
  if (n < NOUT && jj < 400) v = Wl[n * 1200 + seg * 400 + jj];
  (&g_pkl[0][0][0])[i] = f2b(v);
}

__global__ void k_pack_misc(const float* Wih0, const float* bih0, const float* bhh0,
                            const float* Wih1, const float* bih1, const float* bhh1,
                            const float* Wih2, const float* bih2, const float* bhh2) {
  int i = blockIdx.x * blockDim.x + threadIdx.x;
  if (i >= 3 * G4) return;
  int l = i / G4, n = i % G4;
  const float* bi = l == 0 ? bih0 : (l == 1 ? bih1 : bih2);
  const float* bh = l == 0 ? bhh0 : (l == 1 ? bhh1 : bhh2);
  const float* wi = l == 0 ? Wih0 : (l == 1 ? Wih1 : Wih2);
  int kin = l == 0 ? 3 : 403;
  g_bsum[l][n] = bi[n] + bh[n];
  for (int c = 0; c < 3; ++c) g_wx[l][n][c] = wi[n * kin + c];
}

// ---------------- persistent pipelined LSTM ----------------
// 125 WGs: l0 = 25 WGs (64 batches each, wave = mtile), l1/l2 = 50 WGs each
// (32 batches, waves = 2 mtiles x 2 k-halves, split-K via LDS).
// All g_outs traffic sc0sc1 (coherent point); flags fire-and-forget atomics; no fences.
__global__ __launch_bounds__(256, 1) void k_lstm(const float* __restrict__ X) {
  const int wg = blockIdx.x;
  int l, w2;
  if (wg < 25)      { l = 0; w2 = wg; }
  else if (wg < 75) { l = 1; w2 = wg - 25; }
  else              { l = 2; w2 = wg - 75; }

  const int tid = threadIdx.x;
  const int lane = tid & 63;
  const int wv = tid >> 6;
  const int brow = lane & 15;
  const int kg = lane >> 4;

  int jt, bg_wg, mtile, kh, bg_wait;
  if (l == 0) { jt = w2; bg_wg = 0; mtile = wv; kh = 1; bg_wait = wv >> 1; }
  else { bg_wg = w2 & 1; jt = w2 >> 1; kh = wv & 1; mtile = bg_wg * 2 + (wv >> 1); bg_wait = bg_wg; }
  const int jh = jt * 16 + brow;

  const u16* pk = (l == 0) ? &g_pk0[0][0][0] : (l == 1 ? &g_pk1[0][0][0] : &g_pk2[0][0][0]);
  const int nks = (l == 0) ? KS0 : KS12;
  const int kofs = (l == 0) ? 0 : kh * 13;

  bf16x8 Bf[4][13];
#pragma unroll
  for (int g = 0; g < 4; ++g)
#pragma unroll
    for (int ks = 0; ks < 13; ++ks)
      Bf[g][ks] = *(const bf16x8*)&pk[(((g * 25 + jt) * nks + kofs + ks) * 64 + lane) * 8];

  float bsum[4], wxc[4][3];
#pragma unroll
  for (int g = 0; g < 4; ++g) {
    int n = g * 400 + jh;
    bsum[g] = g_bsum[l][n];
    wxc[g][0] = g_wx[l][n][0];
    wxc[g][1] = g_wx[l][n][1];
    wxc[g][2] = g_wx[l][n][2];
  }

  float cst[4] = {0.f, 0.f, 0.f, 0.f};
  const long xbase = (long)(mtile * 16 + kg * 4) * TT * 3;
  // A-operand: byte-constant column base for this wave
  const int colb = ((l == 0) ? 0 : (kh ? l : l - 1) * SEG) + kg * 8;
  const int arow = (mtile * 16 + brow) * TT;      // + t_src
  const bool self_wait = (l == 0) || (kh == 1);   // waits own layer t-1, reads t-1
  const int dostore = (l == 0) || ((kg >> 1) == kh);

  __shared__ float red[4][64][20];

  for (int t = 0; t < TT; ++t) {
    // ---------- x-gate precompute (no deps, off critical path) ----------
    float xg[4][4];
    {
      const float* xp = X + xbase + (long)t * 3;
#pragma unroll
      for (int r = 0; r < 4; ++r) {
        float x0 = xp[(long)r * TT * 3 + 0];
        float x1 = xp[(long)r * TT * 3 + 1];
        float x2 = xp[(long)r * TT * 3 + 2];
#pragma unroll
        for (int g = 0; g < 4; ++g)
          xg[g][r] = bsum[g] + wxc[g][0] * x0 + wxc[g][1] * x1 + wxc[g][2] * x2;
      }
    }

    // ---------- per-wave wait (only the flag THIS wave's MFMA needs) ----------
    const bool doA = self_wait ? (t > 0) : true;
    if (doA) {
      const int* wf = self_wait ? &g_flag[l][bg_wait][t - 1][0]
                                : &g_flag[l - 1][bg_wait][t][0];
      if (wait_flag(wf)) return;
    }

    // ---------- MFMA ----------
    f32x4 acc[4] = {};
    if (doA) {
      const int t_src = self_wait ? (t - 1) : t;
      const u16* rowp = &g_outs[arow + t_src][colb];
      bf16x8 A[13];
#define GL(i, OFF) asm volatile("global_load_dwordx4 %0, %1, off offset:" OFF " sc0 sc1" \
                                : "=v"(A[i]) : "v"(rowp))
      GL(0, "0");   GL(1, "64");  GL(2, "128"); GL(3, "192");
      GL(4, "256"); GL(5, "320"); GL(6, "384"); GL(7, "448");
      GL(8, "512"); GL(9, "576"); GL(10, "640"); GL(11, "704"); GL(12, "768");
#undef GL
      asm volatile("s_waitcnt vmcnt(0)" ::: "memory");
      __builtin_amdgcn_sched_barrier(0);
#pragma unroll
      for (int ks = 0; ks < 13; ++ks)
#pragma unroll
        for (int g = 0; g < 4; ++g)
          acc[g] = __builtin_amdgcn_mfma_f32_16x16x32_bf16(A[ks], Bf[g][ks], acc[g], 0, 0, 0);
    }

    // ---------- split-K reduce (l>0); both waves end with full gacc ----------
    f32x4 gacc[4];
    if (l == 0) {
#pragma unroll
      for (int g = 0; g < 4; ++g) gacc[g] = acc[g];
    } else {
#pragma unroll
      for (int g = 0; g < 4; ++g)
        *(f32x4*)&red[wv][lane][g * 4] = acc[g];
      __syncthreads();
#pragma unroll
      for (int g = 0; g < 4; ++g)
        gacc[g] = acc[g] + *(const f32x4*)&red[wv ^ 1][lane][g * 4];
    }

    // ---------- epilogue: gates -> c,h (c duplicated across kh pair; stores split) ----------
#pragma unroll
    for (int r = 0; r < 4; ++r) {
      float gate[4];
#pragma unroll
      for (int g = 0; g < 4; ++g) gate[g] = gacc[g][r] + xg[g][r];
      float ig = sigm(gate[0]), fg = sigm(gate[1]);
      float gg = tanh_(gate[2]), og = sigm(gate[3]);
      float c = fg * cst[r] + ig * gg;
      cst[r] = c;
      float h = og * tanh_(c);
      if (dostore)
        gstore_sc(&g_outs[(long)(mtile * 16 + kg * 4 + r) * TT + t][l * SEG + jh],
                  (unsigned)f2b(h));
    }

    // ---------- publish (syncthreads drains vmcnt incl. write-through stores) ----------
    __syncthreads();
    if (tid == 0) {
      if (l == 0) { flag_add(&g_flag[0][0][t][0]); flag_add(&g_flag[0][1][t][0]); }
      else        { flag_add(&g_flag[l][bg_wg][t][0]); }
    }
  }
}

// ---------------- final projection: [65536,1248] x [1248,128] ----------------
__global__ __launch_bounds__(256) void k_final(float* __restrict__ out) {
  int mt   = blockIdx.x * 4 + (threadIdx.x >> 6);
  int lane = threadIdx.x & 63;
  int arow = mt * 16 + (lane & 15);
  int kchunk = (lane >> 4) * 8;
  f32x4 acc[8] = {};
  for (int ks = 0; ks < KSL; ++ks) {
    bf16x8 a = *(const bf16x8*)&g_outs[arow][ks * 32 + kchunk];
#pragma unroll
    for (int nt = 0; nt < 8; ++nt) {
      bf16x8 b = *(const bf16x8*)&g_pkl[nt][ks][lane * 8];
      acc[nt] = __builtin_amdgcn_mfma_f32_16x16x32_bf16(a, b, acc[nt], 0, 0, 0);
    }
  }
#pragma unroll
  for (int nt = 0; nt < 8; ++nt) {
    int o = nt * 16 + (lane & 15);
    if (o >= NOUT) continue;
#pragma unroll
    for (int r = 0; r < 4; ++r) {
      int m = mt * 16 + (lane >> 4) * 4 + r;
      out[(long)m * NOUT + o] = acc[nt][r] + g_bl[o];
    }
  }
}

// ---------------- launch ----------------
extern "C" void kernel_launch(void* const* d_in, const int* in_sizes, int n_in,
                              void* d_out, int out_size, void* d_ws, size_t ws_size,
                              hipStream_t stream) {
  const float* X    = (const float*)d_in[0];
  const float* Wih0 = (const float*)d_in[1];
  const float* Whh0 = (const float*)d_in[2];
  const float* bih0 = (const float*)d_in[3];
  const float* bhh0 = (const float*)d_in[4];
  const float* Wih1 = (const float*)d_in[5];
  const float* Whh1 = (const float*)d_in[6];
  const float* bih1 = (const float*)d_in[7];
  const float* bhh1 = (const float*)d_in[8];
  const float* Wih2 = (const float*)d_in[9];
  const float* Whh2 = (const float*)d_in[10];
  const float* bih2 = (const float*)d_in[11];
  const float* bhh2 = (const float*)d_in[12];
  const float* Wl   = (const float*)d_in[13];
  const float* bl   = (const float*)d_in[14];

  k_zero<<<(BB * TT * 24 + 255) / 256, 256, 0, stream>>>();
  k_pack_rec<<<(100 * KS0  * 512 + 255) / 256, 256, 0, stream>>>(nullptr, Whh0, 0, KS0, 3);
  k_pack_rec<<<(100 * KS12 * 512 + 255) / 256, 256, 0, stream>>>(Wih1, Whh1, 1, KS12, 403);
  k_pack_rec<<<(100 * KS12 * 512 + 255) / 256, 256, 0, stream>>>(Wih2, Whh2, 2, KS12, 403);
  k_pack_wl<<<(8 * KSL * 512 + 255) / 256, 256, 0, stream>>>(Wl, bl);
  k_pack_misc<<<(3 * G4 + 255) / 256, 256, 0, stream>>>(Wih0, bih0, bhh0,
                                                        Wih1, bih1, bhh1,
                                                        Wih2, bih2, bhh2);
  k_lstm<<<125, 256, 0, stream>>>(X);
  k_final<<<1024, 256, 0, stream>>>((float*)d_out);
}

// Round 3
// 5159.613 us; speedup vs baseline: 2.6494x; 1.0248x over previous
//
#include <hip/hip_runtime.h>
#include <hip/hip_bf16.h>

// ---------------- sizes ----------------
#define H    400
#define SEG  416          // per-layer feature segment, padded to 13*32
#define G4   1600         // 4*H gate rows
#define TT   1024
#define BB   64
#define NOUT 121
#define KS0  13           // k-steps for K=416
#define KS12 26           // k-steps for K=832
#define FPAD 1248         // 3*SEG
#define KSL  39           // 1248/32
#define NG   25           // producer slots per (layer, batch-group) flag line

typedef __attribute__((ext_vector_type(8))) short bf16x8;
typedef __attribute__((ext_vector_type(4))) float f32x4;
typedef unsigned short u16;

// ---------------- persistent device state ----------------
__device__ __align__(16) u16   g_outs[BB * TT][FPAD];
__device__ __align__(16) u16   g_pk0[100][KS0][512];
__device__ __align__(16) u16   g_pk1[100][KS12][512];
__device__ __align__(16) u16   g_pk2[100][KS12][512];
__device__ __align__(16) u16   g_pkl[8][KSL][512];
__device__ float g_bsum[3][G4];
__device__ float g_wx[3][G4][3];
__device__ float g_bl[128];
// versioned flags: slot jt of group (l*2+bg) holds t+1 after that producer finished step t
__device__ __align__(128) int g_flagw[6][32];
__device__ int   g_abort;

// ---------------- helpers ----------------
__device__ inline u16 f2b(float f) {
  union { float f; unsigned u; } v; v.f = f;
  unsigned r = v.u + 0x7FFF + ((v.u >> 16) & 1);
  return (u16)(r >> 16);
}
__device__ inline float sigm(float x) { return 1.f / (1.f + __expf(-x)); }
__device__ inline float tanh_(float x) { return 2.f * sigm(2.f * x) - 1.f; }

// coherent-point (cross-XCD safe) accessors: sc0 sc1 bypass L1+L2, no inv/wb fences
__device__ inline void gstore_sc(u16* p, unsigned v) {
  asm volatile("global_store_short %0, %1, off sc0 sc1" :: "v"(p), "v"(v) : "memory");
}
__device__ inline void fstore(int* p, int v) {
  asm volatile("global_store_dword %0, %1, off sc0 sc1" :: "v"(p), "v"(v) : "memory");
}
__device__ inline int poll_word(const int* p) {
  int v;
  asm volatile("global_load_dword %0, %1, off sc0 sc1\n\ts_waitcnt vmcnt(0)"
               : "=v"(v) : "v"(p) : "memory");
  return v;
}
// wave-cooperative wait: all NG slots of group >= tv (slot==skip exempt). 1 = abort.
__device__ inline int wait_grp(int grp, int tv, int skip) {
  const int slot = threadIdx.x & 31;        // lanes 32-63 mirror 0-31
  const int* p = &g_flagw[grp][slot];
  const bool act = (slot < NG) && (slot != skip);
  long n = 0;
  for (;;) {
    int v = poll_word(p);
    if (__all((!act) || (v >= tv))) return 0;
    if ((++n & 255) == 0) {
      if (poll_word(&g_abort)) return 1;
      if (n > (1L << 20)) { fstore(&g_abort, 1); return 1; }
    }
  }
}

// ---------------- setup kernels ----------------
__global__ void k_zero() {
  int i = blockIdx.x * blockDim.x + threadIdx.x;
  if (i == 0) g_abort = 0;
  if (i < 6 * 32) (&g_flagw[0][0])[i] = 0;
  if (i < BB * TT * 24) {                  // zero pad columns (cols 400..415 of each segment)
    int r = i / 24, j = i % 24;
    int seg = j >> 3, w = j & 7;
    *(unsigned*)&g_outs[r][seg * SEG + 400 + w * 2] = 0u;
  }
}

__global__ void k_pack_rec(const float* Wih, const float* Whh, int layer,
                           int ksteps, int kin) {
  int i = blockIdx.x * blockDim.x + threadIdx.x;
  int total = 100 * ksteps * 512;
  if (i >= total) return;
  int j = i & 7, lane = (i >> 3) & 63;
  int ks = (i >> 9) % ksteps, nt = (i >> 9) / ksteps;
  int g = nt / 25, jt = nt % 25;
  int n  = g * 400 + jt * 16 + (lane & 15);
  int kk = (lane >> 4) * 8 + j;
  float v = 0.f;
  if (layer == 0) {
    int k = ks * 32 + kk;
    if (k < H) v = Whh[n * H + k];
  } else {
    if (ks < KS0) { int k = ks * 32 + kk;         if (k < H) v = Wih[n * kin + 3 + k]; }
    else          { int k = (ks - KS0) * 32 + kk; if (k < H) v = Whh[n * H + k]; }
  }
  u16* dst = (layer == 0) ? &g_pk0[0][0][0] : (layer == 1 ? &g_pk1[0][0][0] : &g_pk2[0][0][0]);
  dst[i] = f2b(v);
}

__global__ void k_pack_wl(const float* Wl, const float* bl) {
  int i = blockIdx.x * blockDim.x + threadIdx.x;
  if (i < 128) g_bl[i] = (i < NOUT) ? bl[i] : 0.f;
  int total = 8 * KSL * 512;
  if (i >= total) return;
  int j = i & 7, lane = (i >> 3) & 63;
  int ks = (i >> 9) % KSL, nt = (i >> 9) / KSL;
  int n = nt * 16 + (lane & 15);
  int k = ks * 32 + (lane >> 4) * 8 + j;
  int seg = k / SEG, jj = k - seg * SEG;
  float v = 0.f;
  if (n < NOUT && jj < 400) v = Wl[n * 1200 + seg * 400 + jj];
  (&g_pkl[0][0][0])[i] = f2b(v);
}

__global__ void k_pack_misc(const float* Wih0, const float* bih0, const float* bhh0,
                            const float* Wih1, const float* bih1, const float* bhh1,
                            const float* Wih2, const float* bih2, const float* bhh2) {
  int i = blockIdx.x * blockDim.x + threadIdx.x;
  if (i >= 3 * G4) return;
  int l = i / G4, n = i % G4;
  const float* bi = l == 0 ? bih0 : (l == 1 ? bih1 : bih2);
  const float* bh = l == 0 ? bhh0 : (l == 1 ? bhh1 : bhh2);
  const float* wi = l == 0 ? Wih0 : (l == 1 ? Wih1 : Wih2);
  int kin = l == 0 ? 3 : 403;
  g_bsum[l][n] = bi[n] + bh[n];
  for (int c = 0; c < 3; ++c) g_wx[l][n][c] = wi[n * kin + c];
}

// ---------------- persistent pipelined LSTM ----------------
// 125 WGs: l0 = 25 WGs (64 batches, wave = mtile); l1/l2 = 50 WGs each
// (32 batches, waves = 2 mtiles x 2 k-halves, split-K via LDS).
// Sync: versioned per-producer flag words (plain sc0sc1 stores, no atomics);
// each wave polls only the flag its own A-load needs; one drain barrier per step.
__global__ __launch_bounds__(256, 1) void k_lstm(const float* __restrict__ X) {
  const int wg = blockIdx.x;
  int l, w2;
  if (wg < 25)      { l = 0; w2 = wg; }
  else if (wg < 75) { l = 1; w2 = wg - 25; }
  else              { l = 2; w2 = wg - 75; }

  const int tid = threadIdx.x;
  const int lane = tid & 63;
  const int wv = tid >> 6;
  const int brow = lane & 15;
  const int kg = lane >> 4;

  int jt, bg, mtile, kh;
  if (l == 0) { jt = w2; bg = wv >> 1; mtile = wv; kh = 1; }
  else        { bg = w2 & 1; jt = w2 >> 1; kh = wv & 1; mtile = bg * 2 + (wv >> 1); }
  const int jh = jt * 16 + brow;

  const u16* pk = (l == 0) ? &g_pk0[0][0][0] : (l == 1 ? &g_pk1[0][0][0] : &g_pk2[0][0][0]);
  const int nks = (l == 0) ? KS0 : KS12;
  const int kofs = (l == 0) ? 0 : kh * 13;

  bf16x8 Bf[4][13];
#pragma unroll
  for (int g = 0; g < 4; ++g)
#pragma unroll
    for (int ks = 0; ks < 13; ++ks)
      Bf[g][ks] = *(const bf16x8*)&pk[(((g * 25 + jt) * nks + kofs + ks) * 64 + lane) * 8];

  float bsum[4], wxc[4][3];
#pragma unroll
  for (int g = 0; g < 4; ++g) {
    int n = g * 400 + jh;
    bsum[g] = g_bsum[l][n];
    wxc[g][0] = g_wx[l][n][0];
    wxc[g][1] = g_wx[l][n][1];
    wxc[g][2] = g_wx[l][n][2];
  }

  float cst[4] = {0.f, 0.f, 0.f, 0.f};
  const long xbase = (long)(mtile * 16 + kg * 4) * TT * 3;
  const bool self_wait = (l == 0) || (kh == 1);   // reads own layer at t-1
  const int colb = ((l == 0) ? 0 : (kh ? l : l - 1) * SEG) + kg * 8;
  const int arow = (mtile * 16 + brow) * TT;
  const int dostore = (l == 0) || ((kg >> 1) == kh);
  const int grp_self = l * 2 + bg;
  const int grp_low  = (l - 1) * 2 + bg;          // only used when l>0

  __shared__ float red[4][64][20];
  __shared__ int s_ab[4];

  for (int t = 0; t < TT; ++t) {
    // ---------- x-gate precompute (no deps, overlaps wait) ----------
    float xg[4][4];
    {
      const float* xp = X + xbase + (long)t * 3;
#pragma unroll
      for (int r = 0; r < 4; ++r) {
        float x0 = xp[(long)r * TT * 3 + 0];
        float x1 = xp[(long)r * TT * 3 + 1];
        float x2 = xp[(long)r * TT * 3 + 2];
#pragma unroll
        for (int g = 0; g < 4; ++g)
          xg[g][r] = bsum[g] + wxc[g][0] * x0 + wxc[g][1] * x1 + wxc[g][2] * x2;
      }
    }

    // ---------- per-wave wait on exactly the needed flag ----------
    int ab = 0;
    if (self_wait) { if (t > 0) ab = wait_grp(grp_self, t, jt); }
    else           { ab = wait_grp(grp_low, t + 1, -1); }
    if (lane == 0) s_ab[wv] = ab;

    // ---------- MFMA ----------
    const bool doA = self_wait ? (t > 0) : true;
    f32x4 acc[4] = {};
    if (doA) {
      const int t_src = self_wait ? (t - 1) : t;
      const u16* rowp = &g_outs[arow + t_src][colb];
      bf16x8 A[13];
#define GL(i, OFF) asm volatile("global_load_dwordx4 %0, %1, off offset:" OFF " sc0 sc1" \
                                : "=v"(A[i]) : "v"(rowp))
      GL(0, "0");   GL(1, "64");  GL(2, "128"); GL(3, "192");
      GL(4, "256"); GL(5, "320"); GL(6, "384"); GL(7, "448");
      GL(8, "512"); GL(9, "576"); GL(10, "640"); GL(11, "704"); GL(12, "768");
#undef GL
      asm volatile("s_waitcnt vmcnt(0)" ::: "memory");
      __builtin_amdgcn_sched_barrier(0);
#pragma unroll
      for (int ks = 0; ks < 13; ++ks)
#pragma unroll
        for (int g = 0; g < 4; ++g)
          acc[g] = __builtin_amdgcn_mfma_f32_16x16x32_bf16(A[ks], Bf[g][ks], acc[g], 0, 0, 0);
    }

    // ---------- split-K reduce (l>0); both waves end with full gacc ----------
    f32x4 gacc[4];
    if (l == 0) {
#pragma unroll
      for (int g = 0; g < 4; ++g) gacc[g] = acc[g];
    } else {
#pragma unroll
      for (int g = 0; g < 4; ++g)
        *(f32x4*)&red[wv][lane][g * 4] = acc[g];
      __syncthreads();
#pragma unroll
      for (int g = 0; g < 4; ++g)
        gacc[g] = acc[g] + *(const f32x4*)&red[wv ^ 1][lane][g * 4];
    }

    // ---------- epilogue: gates -> c,h ----------
#pragma unroll
    for (int r = 0; r < 4; ++r) {
      float gate[4];
#pragma unroll
      for (int g = 0; g < 4; ++g) gate[g] = gacc[g][r] + xg[g][r];
      float ig = sigm(gate[0]), fg = sigm(gate[1]);
      float gg = tanh_(gate[2]), og = sigm(gate[3]);
      float c = fg * cst[r] + ig * gg;
      cst[r] = c;
      float h = og * tanh_(c);
      if (dostore)
        gstore_sc(&g_outs[(long)(mtile * 16 + kg * 4 + r) * TT + t][l * SEG + jh],
                  (unsigned)f2b(h));
    }

    // ---------- drain + joint abort check + publish ----------
    __syncthreads();   // drains vmcnt (h stores) for all waves; LDS visible
    if (s_ab[0] | s_ab[1] | s_ab[2] | s_ab[3]) return;
    if (tid == 0) {
      if (l == 0) { fstore(&g_flagw[0][jt], t + 1); fstore(&g_flagw[1][jt], t + 1); }
      else        { fstore(&g_flagw[grp_self][jt], t + 1); }
    }
  }
}

// ---------------- final projection: [65536,1248] x [1248,128] ----------------
__global__ __launch_bounds__(256) void k_final(float* __restrict__ out) {
  int mt   = blockIdx.x * 4 + (threadIdx.x >> 6);
  int lane = threadIdx.x & 63;
  int arow = mt * 16 + (lane & 15);
  int kchunk = (lane >> 4) * 8;
  f32x4 acc[8] = {};
  for (int ks = 0; ks < KSL; ++ks) {
    bf16x8 a = *(const bf16x8*)&g_outs[arow][ks * 32 + kchunk];
#pragma unroll
    for (int nt = 0; nt < 8; ++nt) {
      bf16x8 b = *(const bf16x8*)&g_pkl[nt][ks][lane * 8];
      acc[nt] = __builtin_amdgcn_mfma_f32_16x16x32_bf16(a, b, acc[nt], 0, 0, 0);
    }
  }
#pragma unroll
  for (int nt = 0; nt < 8; ++nt) {
    int o = nt * 16 + (lane & 15);
    if (o >= NOUT) continue;
#pragma unroll
    for (int r = 0; r < 4; ++r) {
      int m = mt * 16 + (lane >> 4) * 4 + r;
      out[(long)m * NOUT + o] = acc[nt][r] + g_bl[o];
    }
  }
}

// ---------------- launch ----------------
extern "C" void kernel_launch(void* const* d_in, const int* in_sizes, int n_in,
                              void* d_out, int out_size, void* d_ws, size_t ws_size,
                              hipStream_t stream) {
  const float* X    = (const float*)d_in[0];
  const float* Wih0 = (const float*)d_in[1];
  const float* Whh0 = (const float*)d_in[2];
  const float* bih0 = (const float*)d_in[3];
  const float* bhh0 = (const float*)d_in[4];
  const float* Wih1 = (const float*)d_in[5];
  const float* Whh1 = (const float*)d_in[6];
  const float* bih1 = (const float*)d_in[7];
  const float* bhh1 = (const float*)d_in[8];
  const float* Wih2 = (const float*)d_in[9];
  const float* Whh2 = (const float*)d_in[10];
  const float* bih2 = (const float*)d_in[11];
  const float* bhh2 = (const float*)d_in[12];
  const float* Wl   = (const float*)d_in[13];
  const float* bl   = (const float*)d_in[14];

  k_zero<<<(BB * TT * 24 + 255) / 256, 256, 0, stream>>>();
  k_pack_rec<<<(100 * KS0  * 512 + 255) / 256, 256, 0, stream>>>(nullptr, Whh0, 0, KS0, 3);
  k_pack_rec<<<(100 * KS12 * 512 + 255) / 256, 256, 0, stream>>>(Wih1, Whh1, 1, KS12, 403);
  k_pack_rec<<<(100 * KS12 * 512 + 255) / 256, 256, 0, stream>>>(Wih2, Whh2, 2, KS12, 403);
  k_pack_wl<<<(8 * KSL * 512 + 255) / 256, 256, 0, stream>>>(Wl, bl);
  k_pack_misc<<<(3 * G4 + 255) / 256, 256, 0, stream>>>(Wih0, bih0, bhh0,
                                                        Wih1, bih1, bhh1,
                                                        Wih2, bih2, bhh2);
  k_lstm<<<125, 256, 0, stream>>>(X);
  k_final<<<1024, 256, 0, stream>>>((float*)d_out);
}